// Round 10
// baseline (3868.973 us; speedup 1.0000x reference)
//
#include <hip/hip_runtime.h>
#include <hip/hip_bf16.h>

typedef __attribute__((ext_vector_type(8))) short short8;
typedef __attribute__((ext_vector_type(4))) float f32x4;

#define Bsz   2048
#define Tsz   32
#define Zsz   128
#define Hsz   512
#define Msz   256
#define Nsz   10
#define KDIM  896      // 128 (z) + 256 (rv) + 512 (h)
#define NGATE 2048
#define NHEAD 1040
#define NHEADP 1152

#define ACT_S ((size_t)Bsz * 768)        // per-plane act elements (rv 0-255 | h 256-767)
#define ZPL_S ((size_t)33 * Bsz * 128)   // per-plane znorm elements
#define WG_S  ((size_t)NGATE * KDIM)
#define WH_S  ((size_t)NHEADP * Hsz)

__device__ __forceinline__ float sigmoidf_(float x) { return 1.f / (1.f + expf(-x)); }
__device__ __forceinline__ float softplusf_(float x) { return x > 20.f ? x : log1pf(expf(x)); }

// 3-term bf16 split: v = o1 + o2 + o3 + r, |r| <= 2^-24 |v|
__device__ __forceinline__ void split3(float v, __hip_bfloat16& o1, __hip_bfloat16& o2, __hip_bfloat16& o3) {
    o1 = __float2bfloat16(v);
    float r = v - __bfloat162float(o1);
    o2 = __float2bfloat16(r);
    r -= __bfloat162float(o2);
    o3 = __float2bfloat16(r);
}

#define MFMA16(A, B, C) __builtin_amdgcn_mfma_f32_16x16x32_bf16((A), (B), (C), 0, 0, 0)

// async global -> LDS, 16B per lane; LDS dest = uniform base + lane*16
__device__ __forceinline__ void gload16(const void* g, void* l) {
    __builtin_amdgcn_global_load_lds(
        (const __attribute__((address_space(1))) void*)g,
        (__attribute__((address_space(3))) void*)l, 16, 0, 0);
}

// ---------------- prologue kernels ----------------

__global__ __launch_bounds__(256) void k_lnorm(
    const float* __restrict__ z_seq, const float* __restrict__ gamma,
    const float* __restrict__ beta, __hip_bfloat16* __restrict__ zb)
{
    int idx = blockIdx.x * 256 + threadIdx.x;
    if (idx >= Bsz * Zsz) return;
    int b = idx >> 7, zi = idx & 127;
    const float* p = z_seq + (size_t)b * Tsz * Zsz + zi;
    float v[32];
    float s = 0.f;
#pragma unroll
    for (int t = 0; t < Tsz; t++) { v[t] = p[t * Zsz]; s += v[t]; }
    float mu = s * (1.f / 32.f);
    float ss = 0.f;
#pragma unroll
    for (int t = 0; t < Tsz; t++) { float d = v[t] - mu; ss += d * d; }
    float rs = rsqrtf(ss * (1.f / 31.f) + 1e-8f);
    float ga = gamma[zi], be = beta[zi];
#pragma unroll
    for (int t = 0; t <= Tsz; t++) {
        float val = (t < Tsz) ? (v[t] - mu) * rs * ga + be : 0.f;
        __hip_bfloat16 a, bq, c;
        split3(val, a, bq, c);
        size_t o = ((size_t)t * Bsz + b) * 128 + zi;
        zb[o] = a; zb[o + ZPL_S] = bq; zb[o + 2 * ZPL_S] = c;
    }
}

// Wcat[n][k], n = jg*64 + g*16 + jl  ->  W row r = g*512 + jg*16 + jl   (3 planes)
__global__ __launch_bounds__(256) void k_prep_wcat(
    const float* __restrict__ W_ih, const float* __restrict__ W_hh,
    const float* __restrict__ b_ih, const float* __restrict__ b_hh,
    __hip_bfloat16* __restrict__ Wt, float* __restrict__ bcat)
{
    int idx = blockIdx.x * 256 + threadIdx.x;
    if (idx >= NGATE * KDIM) return;
    int n = idx / KDIM, k = idx % KDIM;
    int jl = n & 15, g = (n >> 4) & 3, jg = n >> 6;
    int r = g * Hsz + jg * 16 + jl;
    float v = (k < 384) ? W_ih[(size_t)r * 384 + k] : W_hh[(size_t)r * Hsz + (k - 384)];
    __hip_bfloat16 a, b, c;
    split3(v, a, b, c);
    Wt[idx] = a; Wt[idx + WG_S] = b; Wt[idx + 2 * WG_S] = c;
    if (k == 0) bcat[n] = b_ih[r] + b_hh[r];
}

struct HeadP { const float* W[13]; const float* b[13]; };

__global__ __launch_bounds__(256) void k_prep_heads(
    HeadP hp, __hip_bfloat16* __restrict__ Wt, float* __restrict__ bh)
{
    int idx = blockIdx.x * 256 + threadIdx.x;
    if (idx >= NHEADP * Hsz) return;
    int n = idx / Hsz, k = idx % Hsz;
    float v = 0.f;
    if (n < NHEAD) {
        const int offs[14] = {0,256,512,768,1024,1028,1029,1030,1031,1032,1035,1038,1039,1040};
        int h = 0;
        while (n >= offs[h + 1]) h++;
        int local = n - offs[h];
        v = hp.W[h][(size_t)local * Hsz + k];
        if (k == 0) bh[n] = hp.b[h][local];
    } else if (k == 0) bh[n] = 0.f;
    __hip_bfloat16 a, b, c;
    split3(v, a, b, c);
    Wt[idx] = a; Wt[idx + WH_S] = b; Wt[idx + 2 * WH_S] = c;
}

__global__ __launch_bounds__(256) void k_init(
    __hip_bfloat16* __restrict__ act,
    float* __restrict__ cbuf, float* __restrict__ w_read, float* __restrict__ w_write,
    float* __restrict__ mem, const float* __restrict__ memory_init)
{
    int tid = blockIdx.x * blockDim.x + threadIdx.x;
    int stride = gridDim.x * blockDim.x;
    const __hip_bfloat16 z0 = __float2bfloat16(0.f);
    for (size_t i = tid; i < 6 * ACT_S; i += stride) act[i] = z0;
    for (int i = tid; i < Bsz * Hsz; i += stride) cbuf[i] = 0.f;
    for (int i = tid; i < Bsz * Nsz; i += stride) { w_read[i] = 0.f; w_write[i] = 0.f; }
    for (int i = tid; i < Bsz * Nsz * Msz; i += stride) mem[i] = memory_init[i % (Nsz * Msz)];
}

// ---------------- split-bf16 MFMA GEMM kernels (R4 exact) ----------------

__device__ __forceinline__ void stage_tile(
    uint8_t* smem, int wid, int lane,
    const __hip_bfloat16* aP0, size_t aPlaneStride, int aRowStride, int aColOff, int row0,
    const __hip_bfloat16* bP0, size_t bPlaneStride, int bRowStride, int n00,
    int k0)
{
    const int row4 = lane >> 2;
    const int sch = (lane & 3) ^ (row4 & 3);
    const int koff = sch << 3;
#pragma unroll
    for (int i = 0; i < 9; ++i) {
        int c = wid * 9 + i;
        if (c < 24) {
            int p = c >> 3, rg = c & 7;
            int row = rg * 16 + row4;
            const __hip_bfloat16* g = aP0 + (size_t)p * aPlaneStride +
                (size_t)(row0 + row) * aRowStride + aColOff + k0 + koff;
            gload16(g, smem + p * 8192 + rg * 1024);
        } else {
            int c2 = c - 24;
            int p = c2 >> 2, rg = c2 & 3;
            int row = rg * 16 + row4;
            const __hip_bfloat16* g = bP0 + (size_t)p * bPlaneStride +
                (size_t)(n00 + row) * bRowStride + k0 + koff;
            gload16(g, smem + 24576 + p * 4096 + rg * 1024);
        }
    }
}

// gates GEMM (M=2048, N=2048, K=896) + fused LSTM epilogue
__global__ __launch_bounds__(256, 2) void k_gates(
    const __hip_bfloat16* __restrict__ zt,
    const __hip_bfloat16* __restrict__ actin,
    const __hip_bfloat16* __restrict__ Wg,
    const float* __restrict__ bcat,
    float* __restrict__ cbuf,
    __hip_bfloat16* __restrict__ actout)
{
    __shared__ __align__(1024) uint8_t smem[36864];
    const int tid = threadIdx.x;
    const int wid = tid >> 6, lane = tid & 63;
    const int fr = lane & 15, kg = lane >> 4;
    const int wr = wid >> 1, wc = wid & 1;
    const int wg = blockIdx.x;
    const int xcd = wg & 7, rr = wg >> 3;
    const int bm = (xcd & 1) * 8 + (rr & 7);
    const int bn = (xcd >> 1) * 8 + (rr >> 3);
    const int row0 = bm * 128, n00 = bn * 64;

    f32x4 acc[4][2];
#pragma unroll
    for (int s = 0; s < 4; ++s)
#pragma unroll
        for (int u = 0; u < 2; ++u) acc[s][u] = f32x4{0.f, 0.f, 0.f, 0.f};

    const int swz = (kg ^ (fr & 3)) << 4;
    constexpr int PA[6] = {0, 0, 1, 0, 1, 2};
    constexpr int PB[6] = {0, 1, 0, 2, 1, 0};

    const int NKT = KDIM / 32;  // 28
    for (int kt = 0; kt < NKT; ++kt) {
        const int k0 = kt * 32;
        if (k0 < 128)
            stage_tile(smem, wid, lane, zt, ZPL_S, 128, 0, row0, Wg, WG_S, KDIM, n00, k0);
        else
            stage_tile(smem, wid, lane, actin, ACT_S, 768, -128, row0, Wg, WG_S, KDIM, n00, k0);
        __syncthreads();

        short8 af[3][4];
#pragma unroll
        for (int p = 0; p < 3; ++p)
#pragma unroll
            for (int s = 0; s < 4; ++s)
                af[p][s] = *(const short8*)(smem + p * 8192 + (wr * 64 + s * 16 + fr) * 64 + swz);
        short8 bf[3][2];
#pragma unroll
        for (int p = 0; p < 3; ++p)
#pragma unroll
            for (int u = 0; u < 2; ++u)
                bf[p][u] = *(const short8*)(smem + 24576 + p * 4096 + (wc * 32 + u * 16 + fr) * 64 + swz);

#pragma unroll
        for (int pr = 0; pr < 6; ++pr)
#pragma unroll
            for (int s = 0; s < 4; ++s)
#pragma unroll
                for (int u = 0; u < 2; ++u)
                    acc[s][u] = MFMA16(af[PA[pr]][s], bf[PB[pr]][u], acc[s][u]);
        __syncthreads();
    }

    float* G = (float*)smem;   // [4 gates][128 rows][17]
#pragma unroll
    for (int s = 0; s < 4; ++s)
#pragma unroll
        for (int u = 0; u < 2; ++u) {
            int g = wc * 2 + u;
#pragma unroll
            for (int r = 0; r < 4; ++r) {
                int row = wr * 64 + s * 16 + kg * 4 + r;
                G[(g * 128 + row) * 17 + fr] = acc[s][u][r];
            }
        }
    __syncthreads();

#pragma unroll
    for (int i = 0; i < 8; ++i) {
        int p2 = i * 256 + tid;
        int row = p2 >> 4, jl = p2 & 15;
        int m = row0 + row;
        int j = bn * 16 + jl;
        float iv = G[(0 * 128 + row) * 17 + jl] + bcat[n00 +  0 + jl];
        float fv = G[(1 * 128 + row) * 17 + jl] + bcat[n00 + 16 + jl];
        float gv = G[(2 * 128 + row) * 17 + jl] + bcat[n00 + 32 + jl];
        float ov = G[(3 * 128 + row) * 17 + jl] + bcat[n00 + 48 + jl];
        size_t ci = (size_t)m * Hsz + j;
        float co = cbuf[ci];
        float cn = sigmoidf_(fv) * co + sigmoidf_(iv) * tanhf(gv);
        float hn = sigmoidf_(ov) * tanhf(cn);
        cbuf[ci] = cn;
        __hip_bfloat16 h1, h2, h3;
        split3(hn, h1, h2, h3);
        size_t ho = (size_t)m * 768 + 256 + j;
        actout[ho] = h1; actout[ho + ACT_S] = h2; actout[ho + 2 * ACT_S] = h3;
    }
}

// heads GEMM (M=2048, N=1152 padded, K=512) -> headbuf fp32 (+bias only)
// nOff: n-block offset (t=32 trim launches grid (16,1) with nOff=16 -> cols 1024-1087)
__global__ __launch_bounds__(256, 2) void k_heads(
    const __hip_bfloat16* __restrict__ actout,
    const __hip_bfloat16* __restrict__ Wh,
    const float* __restrict__ bh,
    float* __restrict__ headbuf,
    int nOff)
{
    __shared__ __align__(1024) uint8_t smem[36864];
    const int tid = threadIdx.x;
    const int wid = tid >> 6, lane = tid & 63;
    const int fr = lane & 15, kg = lane >> 4;
    const int wr = wid >> 1, wc = wid & 1;
    const int bm = blockIdx.x, bn = blockIdx.y + nOff;
    const int row0 = bm * 128, n00 = bn * 64;

    f32x4 acc[4][2];
#pragma unroll
    for (int s = 0; s < 4; ++s)
#pragma unroll
        for (int u = 0; u < 2; ++u) acc[s][u] = f32x4{0.f, 0.f, 0.f, 0.f};

    const int swz = (kg ^ (fr & 3)) << 4;
    constexpr int PA[6] = {0, 0, 1, 0, 1, 2};
    constexpr int PB[6] = {0, 1, 0, 2, 1, 0};

    const int NKT = Hsz / 32;  // 16
    for (int kt = 0; kt < NKT; ++kt) {
        stage_tile(smem, wid, lane, actout, ACT_S, 768, 256, row0, Wh, WH_S, Hsz, n00, kt * 32);
        __syncthreads();

        short8 af[3][4];
#pragma unroll
        for (int p = 0; p < 3; ++p)
#pragma unroll
            for (int s = 0; s < 4; ++s)
                af[p][s] = *(const short8*)(smem + p * 8192 + (wr * 64 + s * 16 + fr) * 64 + swz);
        short8 bf[3][2];
#pragma unroll
        for (int p = 0; p < 3; ++p)
#pragma unroll
            for (int u = 0; u < 2; ++u)
                bf[p][u] = *(const short8*)(smem + 24576 + p * 4096 + (wc * 32 + u * 16 + fr) * 64 + swz);

#pragma unroll
        for (int pr = 0; pr < 6; ++pr)
#pragma unroll
            for (int s = 0; s < 4; ++s)
#pragma unroll
                for (int u = 0; u < 2; ++u)
                    acc[s][u] = MFMA16(af[PA[pr]][s], bf[PB[pr]][u], acc[s][u]);
        __syncthreads();
    }

#pragma unroll
    for (int s = 0; s < 4; ++s)
#pragma unroll
        for (int u = 0; u < 2; ++u) {
            int n = n00 + wc * 32 + u * 16 + fr;
            if (n >= NHEAD) continue;
            float bias = bh[n];
#pragma unroll
            for (int r = 0; r < 4; ++r) {
                int m = row0 + wr * 64 + s * 16 + kg * 4 + r;
                headbuf[(size_t)m * NHEAD + n] = acc[s][u][r] + bias;
            }
        }
}

// ---------------- addressing (fused: reduce + chain + update, one kernel) ----------------

__device__ inline void compute_address(
    const float dot[10], const float mn[10], float kn, float strength, float gate,
    const float sh[3], float sharp, const float* __restrict__ wprev, bool interp,
    float out[10])
{
    float w[10];
    float mx = -1e30f;
#pragma unroll
    for (int n = 0; n < 10; n++) {
        w[n] = strength * (dot[n] / (kn * mn[n]));
        mx = fmaxf(mx, w[n]);
    }
    float s = 0.f;
#pragma unroll
    for (int n = 0; n < 10; n++) { w[n] = expf(w[n] - mx); s += w[n]; }
    float inv = 1.f / s;
#pragma unroll
    for (int n = 0; n < 10; n++) w[n] *= inv;
    if (interp) {
#pragma unroll
        for (int n = 0; n < 10; n++) w[n] = gate * w[n] + (1.f - gate) * wprev[n];
    }
    float w2[10];
#pragma unroll
    for (int n = 0; n < 10; n++) {
        int np1 = (n + 1) % 10, nm1 = (n + 9) % 10;
        w2[n] = sh[0] * w[np1] + sh[1] * w[n] + sh[2] * w[nm1];
    }
    float ssum = 0.f;
#pragma unroll
    for (int n = 0; n < 10; n++) { w2[n] = powf(w2[n], sharp); ssum += w2[n]; }
    float rinv = 1.f / ssum;
#pragma unroll
    for (int n = 0; n < 10; n++) out[n] = w2[n] * rinv;
}

// Phase1 (all 256 thr): mem loads -> LDS-transpose reduce (R6/R7-proven).
// Phase2 (wave 0): addressing chain, share wfr/wfw via LDS.
// Phase3 (all): rv + mem update; mreg stays in registers throughout.
__global__ __launch_bounds__(256) void k_addr2(
    const float* __restrict__ headbuf,   // B x 1040 (raw)
    float* __restrict__ mem,             // B x 10 x 256
    float* __restrict__ w_read, float* __restrict__ w_write,  // B x 10 state
    __hip_bfloat16* __restrict__ actout, // rv -> cols 0-255, 3 planes
    int t)
{
    const int b = blockIdx.x;
    const int tid = threadIdx.x;
    const int wid = tid >> 6, lane = tid & 63;
    const float eps = 1e-8f;
    const float* hb = headbuf + (size_t)b * NHEAD;
    float* memb = mem + (size_t)b * Nsz * Msz;

    __shared__ float P[32][257];
    __shared__ float fin[32];
    __shared__ float W2[20];   // wfr[10] | wfw[10]

    const float rk = tanhf(hb[tid]);
    const float wk = tanhf(hb[256 + tid]);
    const float er = sigmoidf_(hb[512 + tid]);
    const float ad = tanhf(hb[768 + tid]);

    float mreg[10];
#pragma unroll
    for (int n = 0; n < 10; n++) {
        float mv = memb[n * Msz + tid];
        mreg[n] = mv;
        P[n][tid]      = rk * mv;
        P[10 + n][tid] = wk * mv;
        P[20 + n][tid] = mv * mv;
    }
    P[30][tid] = rk * rk;
    P[31][tid] = wk * wk;
    __syncthreads();

    {
        const int s = tid >> 3, c = tid & 7;
        float v = 0.f;
#pragma unroll
        for (int i = 0; i < 32; ++i)
            v += P[s][c * 32 + ((i + 4 * c) & 31)];
        v += __shfl_xor(v, 1, 64);
        v += __shfl_xor(v, 2, 64);
        v += __shfl_xor(v, 4, 64);
        if (c == 0) fin[s] = v;
    }
    __syncthreads();

    if (wid == 0) {
        float dotr[10], dotw[10], mn[10];
#pragma unroll
        for (int n = 0; n < 10; n++) {
            dotr[n] = fin[n];
            dotw[n] = fin[10 + n];
            mn[n] = fmaxf(sqrtf(fin[20 + n]), eps);
        }
        const float knr = fmaxf(sqrtf(fin[30]), eps);
        const float knw = fmaxf(sqrtf(fin[31]), eps);

        float rks = softplusf_(hb[1028]);
        float wks = softplusf_(hb[1029]);
        float rig = sigmoidf_(hb[1030]);
        float wig = sigmoidf_(hb[1031]);
        float rsh[3], wsh[3];
        {
            float a0 = hb[1032], a1 = hb[1033], a2 = hb[1034];
            float mx = fmaxf(a0, fmaxf(a1, a2));
            float e0 = expf(a0 - mx), e1 = expf(a1 - mx), e2 = expf(a2 - mx);
            float inv = 1.f / (e0 + e1 + e2);
            rsh[0] = e0 * inv; rsh[1] = e1 * inv; rsh[2] = e2 * inv;
            a0 = hb[1035]; a1 = hb[1036]; a2 = hb[1037];
            mx = fmaxf(a0, fmaxf(a1, a2));
            e0 = expf(a0 - mx); e1 = expf(a1 - mx); e2 = expf(a2 - mx);
            inv = 1.f / (e0 + e1 + e2);
            wsh[0] = e0 * inv; wsh[1] = e1 * inv; wsh[2] = e2 * inv;
        }
        float rshp = softplusf_(hb[1038]) + 1.f;
        float wshp = softplusf_(hb[1039]) + 1.f;

        float wfr[10], wfw[10];
        compute_address(dotr, mn, knr, rks, rig, rsh, rshp, w_read + (size_t)b * Nsz, t > 1, wfr);
        compute_address(dotw, mn, knw, wks, wig, wsh, wshp, w_write + (size_t)b * Nsz, t > 0, wfw);

        if (lane < 10) {
            W2[lane] = wfr[lane];
            W2[10 + lane] = wfw[lane];
            if (t != 0) w_read[(size_t)b * Nsz + lane] = wfr[lane];
            w_write[(size_t)b * Nsz + lane] = wfw[lane];
        }
    }
    __syncthreads();

    // read_vec from OLD mem (registers) -> split-bf16 planes
    {
        float rv = 0.f;
#pragma unroll
        for (int n = 0; n < 10; n++) rv += mreg[n] * W2[n];
        if (t == 0) rv = 0.f;
        __hip_bfloat16 r1, r2, r3;
        split3(rv, r1, r2, r3);
        size_t o = (size_t)b * 768 + tid;
        actout[o] = r1; actout[o + ACT_S] = r2; actout[o + 2 * ACT_S] = r3;
    }
    // memory update
#pragma unroll
    for (int n = 0; n < 10; n++) {
        float wwn = W2[10 + n];
        memb[n * Msz + tid] = mreg[n] * (1.f - er * wwn) + ad * wwn;
    }
}

// final output: y logits + argmax from headbuf (t=32)
__global__ __launch_bounds__(64) void k_out(
    const float* __restrict__ headbuf, float* __restrict__ d_out)
{
    int b = blockIdx.x * 64 + threadIdx.x;
    if (b >= Bsz) return;
    float4 y = *reinterpret_cast<const float4*>(headbuf + (size_t)b * NHEAD + 1024);
    d_out[(size_t)b * 4 + 0] = y.x;
    d_out[(size_t)b * 4 + 1] = y.y;
    d_out[(size_t)b * 4 + 2] = y.z;
    d_out[(size_t)b * 4 + 3] = y.w;
    int idx = 0; float best = y.x;
    if (y.y > best) { best = y.y; idx = 1; }
    if (y.z > best) { best = y.z; idx = 2; }
    if (y.w > best) { best = y.w; idx = 3; }
    d_out[Bsz * 4 + b] = (float)idx;
}

// ---------------- host ----------------

extern "C" void kernel_launch(void* const* d_in, const int* in_sizes, int n_in,
                              void* d_out, int out_size, void* d_ws, size_t ws_size,
                              hipStream_t stream) {
    const float* z_seq = (const float*)d_in[0];
    const float* W_ih  = (const float*)d_in[1];
    const float* W_hh  = (const float*)d_in[2];
    const float* b_ih  = (const float*)d_in[3];
    const float* b_hh  = (const float*)d_in[4];
    const float* memory_init = (const float*)d_in[31];
    const float* gamma = (const float*)d_in[32];
    const float* beta  = (const float*)d_in[33];

    HeadP hp;
    for (int i = 0; i < 13; i++) {
        hp.W[i] = (const float*)d_in[5 + 2 * i];
        hp.b[i] = (const float*)d_in[6 + 2 * i];
    }

    char* ws = (char*)d_ws;
    size_t off = 0;
    auto alloc = [&](size_t bytes) -> void* {
        off = (off + 255) & ~(size_t)255;
        void* p = ws + off;
        off += bytes;
        return p;
    };
    __hip_bfloat16* zbuf  = (__hip_bfloat16*)alloc(3 * ZPL_S * 2);
    __hip_bfloat16* act   = (__hip_bfloat16*)alloc(2 * 3 * ACT_S * 2);
    float* cbuf    = (float*)alloc((size_t)Bsz * Hsz * 4);
    float* mem     = (float*)alloc((size_t)Bsz * Nsz * Msz * 4);
    float* w_read  = (float*)alloc((size_t)Bsz * Nsz * 4);
    float* w_write = (float*)alloc((size_t)Bsz * Nsz * 4);
    float* headbuf = (float*)alloc((size_t)Bsz * NHEAD * 4);
    __hip_bfloat16* Wg = (__hip_bfloat16*)alloc(3 * WG_S * 2);
    float* bcat    = (float*)alloc((size_t)NGATE * 4);
    __hip_bfloat16* Wh = (__hip_bfloat16*)alloc(3 * WH_S * 2);
    float* bhead   = (float*)alloc((size_t)NHEADP * 4);

    k_prep_wcat<<<(NGATE * KDIM + 255) / 256, 256, 0, stream>>>(W_ih, W_hh, b_ih, b_hh, Wg, bcat);
    k_prep_heads<<<(NHEADP * Hsz + 255) / 256, 256, 0, stream>>>(hp, Wh, bhead);
    k_lnorm<<<(Bsz * Zsz + 255) / 256, 256, 0, stream>>>(z_seq, gamma, beta, zbuf);
    k_init<<<2048, 256, 0, stream>>>(act, cbuf, w_read, w_write, mem, memory_init);

    float* out_f = (float*)d_out;
    for (int t = 0; t < Tsz; t++) {
        const __hip_bfloat16* ain = act + (size_t)(t & 1) * 3 * ACT_S;
        __hip_bfloat16*       aout = act + (size_t)((t + 1) & 1) * 3 * ACT_S;
        k_gates<<<512, 256, 0, stream>>>(
            zbuf + (size_t)t * Bsz * 128, ain, Wg, bcat, cbuf, aout);
        k_heads<<<dim3(16, 18), 256, 0, stream>>>(aout, Wh, bhead, headbuf, 0);
        k_addr2<<<Bsz, 256, 0, stream>>>(headbuf, mem, w_read, w_write, aout, t);
    }
    // t = 32: only y head needed
    {
        const int t = Tsz;
        const __hip_bfloat16* ain = act + (size_t)(t & 1) * 3 * ACT_S;
        __hip_bfloat16*       aout = act + (size_t)((t + 1) & 1) * 3 * ACT_S;
        k_gates<<<512, 256, 0, stream>>>(
            zbuf + (size_t)t * Bsz * 128, ain, Wg, bcat, cbuf, aout);
        k_heads<<<dim3(16, 1), 256, 0, stream>>>(aout, Wh, bhead, headbuf, 16);
        k_out<<<Bsz / 64, 64, 0, stream>>>(headbuf, out_f);
    }
}

// Round 11
// 3408.122 us; speedup vs baseline: 1.1352x; 1.1352x over previous
//
#include <hip/hip_runtime.h>
#include <hip/hip_bf16.h>

typedef __attribute__((ext_vector_type(8))) short short8;
typedef __attribute__((ext_vector_type(4))) float f32x4;

#define Bsz   2048
#define Tsz   32
#define Zsz   128
#define Hsz   512
#define Msz   256
#define Nsz   10
#define KDIM  896      // 128 (z) + 256 (rv) + 512 (h)
#define NGATE 2048
#define NHEAD 1040
#define NHEADP 1152

#define ACT_S ((size_t)Bsz * 768)        // per-plane act elements (rv 0-255 | h 256-767)
#define ZPL_S ((size_t)33 * Bsz * 128)   // per-plane znorm elements
#define WG_S  ((size_t)NGATE * KDIM)
#define WH_S  ((size_t)NHEADP * Hsz)

__device__ __forceinline__ float sigmoidf_(float x) { return 1.f / (1.f + expf(-x)); }
__device__ __forceinline__ float softplusf_(float x) { return x > 20.f ? x : log1pf(expf(x)); }

__device__ __forceinline__ float wave_sum(float v) {
#pragma unroll
    for (int m = 32; m >= 1; m >>= 1) v += __shfl_xor(v, m, 64);
    return v;
}

// 3-term bf16 split: v = o1 + o2 + o3 + r, |r| <= 2^-24 |v|
__device__ __forceinline__ void split3(float v, __hip_bfloat16& o1, __hip_bfloat16& o2, __hip_bfloat16& o3) {
    o1 = __float2bfloat16(v);
    float r = v - __bfloat162float(o1);
    o2 = __float2bfloat16(r);
    r -= __bfloat162float(o2);
    o3 = __float2bfloat16(r);
}

__device__ __forceinline__ void split3u(float v, unsigned short& a, unsigned short& b, unsigned short& c) {
    __hip_bfloat16 x, y, z;
    split3(v, x, y, z);
    a = *reinterpret_cast<unsigned short*>(&x);
    b = *reinterpret_cast<unsigned short*>(&y);
    c = *reinterpret_cast<unsigned short*>(&z);
}

#define MFMA16(A, B, C) __builtin_amdgcn_mfma_f32_16x16x32_bf16((A), (B), (C), 0, 0, 0)

// async global -> LDS, 16B per lane; LDS dest = uniform base + lane*16
__device__ __forceinline__ void gload16(const void* g, void* l) {
    __builtin_amdgcn_global_load_lds(
        (const __attribute__((address_space(1))) void*)g,
        (__attribute__((address_space(3))) void*)l, 16, 0, 0);
}

// ---------------- prologue kernels ----------------

__global__ __launch_bounds__(256) void k_lnorm(
    const float* __restrict__ z_seq, const float* __restrict__ gamma,
    const float* __restrict__ beta, __hip_bfloat16* __restrict__ zb)
{
    int idx = blockIdx.x * 256 + threadIdx.x;
    if (idx >= Bsz * Zsz) return;
    int b = idx >> 7, zi = idx & 127;
    const float* p = z_seq + (size_t)b * Tsz * Zsz + zi;
    float v[32];
    float s = 0.f;
#pragma unroll
    for (int t = 0; t < Tsz; t++) { v[t] = p[t * Zsz]; s += v[t]; }
    float mu = s * (1.f / 32.f);
    float ss = 0.f;
#pragma unroll
    for (int t = 0; t < Tsz; t++) { float d = v[t] - mu; ss += d * d; }
    float rs = rsqrtf(ss * (1.f / 31.f) + 1e-8f);
    float ga = gamma[zi], be = beta[zi];
#pragma unroll
    for (int t = 0; t <= Tsz; t++) {
        float val = (t < Tsz) ? (v[t] - mu) * rs * ga + be : 0.f;
        __hip_bfloat16 a, bq, c;
        split3(val, a, bq, c);
        size_t o = ((size_t)t * Bsz + b) * 128 + zi;
        zb[o] = a; zb[o + ZPL_S] = bq; zb[o + 2 * ZPL_S] = c;
    }
}

// Wcat[n][k], n = jg*64 + g*16 + jl  ->  W row r = g*512 + jg*16 + jl   (3 planes)
__global__ __launch_bounds__(256) void k_prep_wcat(
    const float* __restrict__ W_ih, const float* __restrict__ W_hh,
    const float* __restrict__ b_ih, const float* __restrict__ b_hh,
    __hip_bfloat16* __restrict__ Wt, float* __restrict__ bcat)
{
    int idx = blockIdx.x * 256 + threadIdx.x;
    if (idx >= NGATE * KDIM) return;
    int n = idx / KDIM, k = idx % KDIM;
    int jl = n & 15, g = (n >> 4) & 3, jg = n >> 6;
    int r = g * Hsz + jg * 16 + jl;
    float v = (k < 384) ? W_ih[(size_t)r * 384 + k] : W_hh[(size_t)r * Hsz + (k - 384)];
    __hip_bfloat16 a, b, c;
    split3(v, a, b, c);
    Wt[idx] = a; Wt[idx + WG_S] = b; Wt[idx + 2 * WG_S] = c;
    if (k == 0) bcat[n] = b_ih[r] + b_hh[r];
}

struct HeadP { const float* W[13]; const float* b[13]; };

__global__ __launch_bounds__(256) void k_prep_heads(
    HeadP hp, __hip_bfloat16* __restrict__ Wt, float* __restrict__ bh)
{
    int idx = blockIdx.x * 256 + threadIdx.x;
    if (idx >= NHEADP * Hsz) return;
    int n = idx / Hsz, k = idx % Hsz;
    float v = 0.f;
    if (n < NHEAD) {
        const int offs[14] = {0,256,512,768,1024,1028,1029,1030,1031,1032,1035,1038,1039,1040};
        int h = 0;
        while (n >= offs[h + 1]) h++;
        int local = n - offs[h];
        v = hp.W[h][(size_t)local * Hsz + k];
        if (k == 0) bh[n] = hp.b[h][local];
    } else if (k == 0) bh[n] = 0.f;
    __hip_bfloat16 a, b, c;
    split3(v, a, b, c);
    Wt[idx] = a; Wt[idx + WH_S] = b; Wt[idx + 2 * WH_S] = c;
}

__global__ __launch_bounds__(256) void k_init(
    __hip_bfloat16* __restrict__ act,
    float* __restrict__ cbuf, float* __restrict__ w_read, float* __restrict__ w_write,
    float* __restrict__ mem, const float* __restrict__ memory_init)
{
    int tid = blockIdx.x * blockDim.x + threadIdx.x;
    int stride = gridDim.x * blockDim.x;
    const __hip_bfloat16 z0 = __float2bfloat16(0.f);
    for (size_t i = tid; i < 6 * ACT_S; i += stride) act[i] = z0;
    for (int i = tid; i < Bsz * Hsz; i += stride) cbuf[i] = 0.f;
    for (int i = tid; i < Bsz * Nsz; i += stride) { w_read[i] = 0.f; w_write[i] = 0.f; }
    for (int i = tid; i < Bsz * Nsz * Msz; i += stride) mem[i] = memory_init[i % (Nsz * Msz)];
}

// ---------------- split-bf16 MFMA GEMM kernels (R4 exact) ----------------

__device__ __forceinline__ void stage_tile(
    uint8_t* smem, int wid, int lane,
    const __hip_bfloat16* aP0, size_t aPlaneStride, int aRowStride, int aColOff, int row0,
    const __hip_bfloat16* bP0, size_t bPlaneStride, int bRowStride, int n00,
    int k0)
{
    const int row4 = lane >> 2;
    const int sch = (lane & 3) ^ (row4 & 3);
    const int koff = sch << 3;
#pragma unroll
    for (int i = 0; i < 9; ++i) {
        int c = wid * 9 + i;
        if (c < 24) {
            int p = c >> 3, rg = c & 7;
            int row = rg * 16 + row4;
            const __hip_bfloat16* g = aP0 + (size_t)p * aPlaneStride +
                (size_t)(row0 + row) * aRowStride + aColOff + k0 + koff;
            gload16(g, smem + p * 8192 + rg * 1024);
        } else {
            int c2 = c - 24;
            int p = c2 >> 2, rg = c2 & 3;
            int row = rg * 16 + row4;
            const __hip_bfloat16* g = bP0 + (size_t)p * bPlaneStride +
                (size_t)(n00 + row) * bRowStride + k0 + koff;
            gload16(g, smem + 24576 + p * 4096 + rg * 1024);
        }
    }
}

// gates GEMM (M=2048, N=2048, K=896) + fused LSTM epilogue
__global__ __launch_bounds__(256, 2) void k_gates(
    const __hip_bfloat16* __restrict__ zt,
    const __hip_bfloat16* __restrict__ actin,
    const __hip_bfloat16* __restrict__ Wg,
    const float* __restrict__ bcat,
    float* __restrict__ cbuf,
    __hip_bfloat16* __restrict__ actout)
{
    __shared__ __align__(1024) uint8_t smem[36864];
    const int tid = threadIdx.x;
    const int wid = tid >> 6, lane = tid & 63;
    const int fr = lane & 15, kg = lane >> 4;
    const int wr = wid >> 1, wc = wid & 1;
    const int wg = blockIdx.x;
    const int xcd = wg & 7, rr = wg >> 3;
    const int bm = (xcd & 1) * 8 + (rr & 7);
    const int bn = (xcd >> 1) * 8 + (rr >> 3);
    const int row0 = bm * 128, n00 = bn * 64;

    f32x4 acc[4][2];
#pragma unroll
    for (int s = 0; s < 4; ++s)
#pragma unroll
        for (int u = 0; u < 2; ++u) acc[s][u] = f32x4{0.f, 0.f, 0.f, 0.f};

    const int swz = (kg ^ (fr & 3)) << 4;
    constexpr int PA[6] = {0, 0, 1, 0, 1, 2};
    constexpr int PB[6] = {0, 1, 0, 2, 1, 0};

    const int NKT = KDIM / 32;  // 28
    for (int kt = 0; kt < NKT; ++kt) {
        const int k0 = kt * 32;
        if (k0 < 128)
            stage_tile(smem, wid, lane, zt, ZPL_S, 128, 0, row0, Wg, WG_S, KDIM, n00, k0);
        else
            stage_tile(smem, wid, lane, actin, ACT_S, 768, -128, row0, Wg, WG_S, KDIM, n00, k0);
        __syncthreads();

        short8 af[3][4];
#pragma unroll
        for (int p = 0; p < 3; ++p)
#pragma unroll
            for (int s = 0; s < 4; ++s)
                af[p][s] = *(const short8*)(smem + p * 8192 + (wr * 64 + s * 16 + fr) * 64 + swz);
        short8 bf[3][2];
#pragma unroll
        for (int p = 0; p < 3; ++p)
#pragma unroll
            for (int u = 0; u < 2; ++u)
                bf[p][u] = *(const short8*)(smem + 24576 + p * 4096 + (wc * 32 + u * 16 + fr) * 64 + swz);

#pragma unroll
        for (int pr = 0; pr < 6; ++pr)
#pragma unroll
            for (int s = 0; s < 4; ++s)
#pragma unroll
                for (int u = 0; u < 2; ++u)
                    acc[s][u] = MFMA16(af[PA[pr]][s], bf[PB[pr]][u], acc[s][u]);
        __syncthreads();
    }

    float* G = (float*)smem;   // [4 gates][128 rows][17]
#pragma unroll
    for (int s = 0; s < 4; ++s)
#pragma unroll
        for (int u = 0; u < 2; ++u) {
            int g = wc * 2 + u;
#pragma unroll
            for (int r = 0; r < 4; ++r) {
                int row = wr * 64 + s * 16 + kg * 4 + r;
                G[(g * 128 + row) * 17 + fr] = acc[s][u][r];
            }
        }
    __syncthreads();

#pragma unroll
    for (int i = 0; i < 8; ++i) {
        int p2 = i * 256 + tid;
        int row = p2 >> 4, jl = p2 & 15;
        int m = row0 + row;
        int j = bn * 16 + jl;
        float iv = G[(0 * 128 + row) * 17 + jl] + bcat[n00 +  0 + jl];
        float fv = G[(1 * 128 + row) * 17 + jl] + bcat[n00 + 16 + jl];
        float gv = G[(2 * 128 + row) * 17 + jl] + bcat[n00 + 32 + jl];
        float ov = G[(3 * 128 + row) * 17 + jl] + bcat[n00 + 48 + jl];
        size_t ci = (size_t)m * Hsz + j;
        float co = cbuf[ci];
        float cn = sigmoidf_(fv) * co + sigmoidf_(iv) * tanhf(gv);
        float hn = sigmoidf_(ov) * tanhf(cn);
        cbuf[ci] = cn;
        __hip_bfloat16 h1, h2, h3;
        split3(hn, h1, h2, h3);
        size_t ho = (size_t)m * 768 + 256 + j;
        actout[ho] = h1; actout[ho + ACT_S] = h2; actout[ho + 2 * ACT_S] = h3;
    }
}

// heads GEMM (M=2048, N=1152 padded, K=512) -> headbuf fp32 (+bias only)
// nOff: n-block offset (t=32 trim launches grid (16,1) with nOff=16 -> cols 1024-1087)
__global__ __launch_bounds__(256, 2) void k_heads(
    const __hip_bfloat16* __restrict__ actout,
    const __hip_bfloat16* __restrict__ Wh,
    const float* __restrict__ bh,
    float* __restrict__ headbuf,
    int nOff)
{
    __shared__ __align__(1024) uint8_t smem[36864];
    const int tid = threadIdx.x;
    const int wid = tid >> 6, lane = tid & 63;
    const int fr = lane & 15, kg = lane >> 4;
    const int wr = wid >> 1, wc = wid & 1;
    const int bm = blockIdx.x, bn = blockIdx.y + nOff;
    const int row0 = bm * 128, n00 = bn * 64;

    f32x4 acc[4][2];
#pragma unroll
    for (int s = 0; s < 4; ++s)
#pragma unroll
        for (int u = 0; u < 2; ++u) acc[s][u] = f32x4{0.f, 0.f, 0.f, 0.f};

    const int swz = (kg ^ (fr & 3)) << 4;
    constexpr int PA[6] = {0, 0, 1, 0, 1, 2};
    constexpr int PB[6] = {0, 1, 0, 2, 1, 0};

    const int NKT = Hsz / 32;  // 16
    for (int kt = 0; kt < NKT; ++kt) {
        stage_tile(smem, wid, lane, actout, ACT_S, 768, 256, row0, Wh, WH_S, Hsz, n00, kt * 32);
        __syncthreads();

        short8 af[3][4];
#pragma unroll
        for (int p = 0; p < 3; ++p)
#pragma unroll
            for (int s = 0; s < 4; ++s)
                af[p][s] = *(const short8*)(smem + p * 8192 + (wr * 64 + s * 16 + fr) * 64 + swz);
        short8 bf[3][2];
#pragma unroll
        for (int p = 0; p < 3; ++p)
#pragma unroll
            for (int u = 0; u < 2; ++u)
                bf[p][u] = *(const short8*)(smem + 24576 + p * 4096 + (wc * 32 + u * 16 + fr) * 64 + swz);

#pragma unroll
        for (int pr = 0; pr < 6; ++pr)
#pragma unroll
            for (int s = 0; s < 4; ++s)
#pragma unroll
                for (int u = 0; u < 2; ++u)
                    acc[s][u] = MFMA16(af[PA[pr]][s], bf[PB[pr]][u], acc[s][u]);
        __syncthreads();
    }

#pragma unroll
    for (int s = 0; s < 4; ++s)
#pragma unroll
        for (int u = 0; u < 2; ++u) {
            int n = n00 + wc * 32 + u * 16 + fr;
            if (n >= NHEAD) continue;
            float bias = bh[n];
#pragma unroll
            for (int r = 0; r < 4; ++r) {
                int m = row0 + wr * 64 + s * 16 + kg * 4 + r;
                headbuf[(size_t)m * NHEAD + n] = acc[s][u][r] + bias;
            }
        }
}

// ---------------- addressing (1 wave / row, fully vectorized float4) ----------------

__device__ inline void compute_address(
    const float dot[10], const float mn[10], float kn, float strength, float gate,
    const float sh[3], float sharp, const float* __restrict__ wprev, bool interp,
    float out[10])
{
    float w[10];
    float mx = -1e30f;
#pragma unroll
    for (int n = 0; n < 10; n++) {
        w[n] = strength * (dot[n] / (kn * mn[n]));
        mx = fmaxf(mx, w[n]);
    }
    float s = 0.f;
#pragma unroll
    for (int n = 0; n < 10; n++) { w[n] = expf(w[n] - mx); s += w[n]; }
    float inv = 1.f / s;
#pragma unroll
    for (int n = 0; n < 10; n++) w[n] *= inv;
    if (interp) {
#pragma unroll
        for (int n = 0; n < 10; n++) w[n] = gate * w[n] + (1.f - gate) * wprev[n];
    }
    float w2[10];
#pragma unroll
    for (int n = 0; n < 10; n++) {
        int np1 = (n + 1) % 10, nm1 = (n + 9) % 10;
        w2[n] = sh[0] * w[np1] + sh[1] * w[n] + sh[2] * w[nm1];
    }
    float ssum = 0.f;
#pragma unroll
    for (int n = 0; n < 10; n++) { w2[n] = powf(w2[n], sharp); ssum += w2[n]; }
    float rinv = 1.f / ssum;
#pragma unroll
    for (int n = 0; n < 10; n++) out[n] = w2[n] * rinv;
}

__global__ __launch_bounds__(64) void k_addr3(
    const float* __restrict__ headbuf,   // B x 1040 (raw)
    float* __restrict__ mem,             // B x 10 x 256
    float* __restrict__ w_read, float* __restrict__ w_write,  // B x 10 state
    __hip_bfloat16* __restrict__ actout, // rv -> cols 0-255, 3 planes
    int t)
{
    const int b = blockIdx.x;
    const int lane = threadIdx.x;        // owns cols lane*4 .. lane*4+3
    const float eps = 1e-8f;
    const float* hb = headbuf + (size_t)b * NHEAD;
    float* memb = mem + (size_t)b * Nsz * Msz;

    // vectorized loads (16B per lane)
    float4 rk = *reinterpret_cast<const float4*>(hb + lane * 4);
    float4 wk = *reinterpret_cast<const float4*>(hb + 256 + lane * 4);
    float4 er = *reinterpret_cast<const float4*>(hb + 512 + lane * 4);
    float4 ad = *reinterpret_cast<const float4*>(hb + 768 + lane * 4);
    float4 mreg[10];
#pragma unroll
    for (int n = 0; n < 10; n++)
        mreg[n] = *reinterpret_cast<const float4*>(memb + n * Msz + lane * 4);

    rk.x = tanhf(rk.x); rk.y = tanhf(rk.y); rk.z = tanhf(rk.z); rk.w = tanhf(rk.w);
    wk.x = tanhf(wk.x); wk.y = tanhf(wk.y); wk.z = tanhf(wk.z); wk.w = tanhf(wk.w);
    er.x = sigmoidf_(er.x); er.y = sigmoidf_(er.y); er.z = sigmoidf_(er.z); er.w = sigmoidf_(er.w);
    ad.x = tanhf(ad.x); ad.y = tanhf(ad.y); ad.z = tanhf(ad.z); ad.w = tanhf(ad.w);

    // reductions: per-lane 4-wide partial, then 64-lane tree (32 wave_sums)
    float knr = fmaxf(sqrtf(wave_sum(rk.x*rk.x + rk.y*rk.y + rk.z*rk.z + rk.w*rk.w)), eps);
    float knw = fmaxf(sqrtf(wave_sum(wk.x*wk.x + wk.y*wk.y + wk.z*wk.z + wk.w*wk.w)), eps);

    float dotr[10], dotw[10], mn[10];
#pragma unroll
    for (int n = 0; n < 10; n++) {
        float4 m4 = mreg[n];
        dotr[n] = wave_sum(rk.x*m4.x + rk.y*m4.y + rk.z*m4.z + rk.w*m4.w);
        dotw[n] = wave_sum(wk.x*m4.x + wk.y*m4.y + wk.z*m4.z + wk.w*m4.w);
        mn[n]   = fmaxf(sqrtf(wave_sum(m4.x*m4.x + m4.y*m4.y + m4.z*m4.z + m4.w*m4.w)), eps);
    }

    float rks = softplusf_(hb[1028]);
    float wks = softplusf_(hb[1029]);
    float rig = sigmoidf_(hb[1030]);
    float wig = sigmoidf_(hb[1031]);
    float rsh[3], wsh[3];
    {
        float a0 = hb[1032], a1 = hb[1033], a2 = hb[1034];
        float mx = fmaxf(a0, fmaxf(a1, a2));
        float e0 = expf(a0 - mx), e1 = expf(a1 - mx), e2 = expf(a2 - mx);
        float inv = 1.f / (e0 + e1 + e2);
        rsh[0] = e0 * inv; rsh[1] = e1 * inv; rsh[2] = e2 * inv;
        a0 = hb[1035]; a1 = hb[1036]; a2 = hb[1037];
        mx = fmaxf(a0, fmaxf(a1, a2));
        e0 = expf(a0 - mx); e1 = expf(a1 - mx); e2 = expf(a2 - mx);
        inv = 1.f / (e0 + e1 + e2);
        wsh[0] = e0 * inv; wsh[1] = e1 * inv; wsh[2] = e2 * inv;
    }
    float rshp = softplusf_(hb[1038]) + 1.f;
    float wshp = softplusf_(hb[1039]) + 1.f;

    float wfr[10], wfw[10];
    compute_address(dotr, mn, knr, rks, rig, rsh, rshp, w_read + (size_t)b * Nsz, t > 1, wfr);
    compute_address(dotw, mn, knw, wks, wig, wsh, wshp, w_write + (size_t)b * Nsz, t > 0, wfw);

    // read_vec from OLD mem (registers) -> split-bf16 planes, 8B packed stores
    {
        float4 rv = {0.f, 0.f, 0.f, 0.f};
#pragma unroll
        for (int n = 0; n < 10; n++) {
            float wn = wfr[n];
            rv.x += mreg[n].x * wn; rv.y += mreg[n].y * wn;
            rv.z += mreg[n].z * wn; rv.w += mreg[n].w * wn;
        }
        if (t == 0) rv = float4{0.f, 0.f, 0.f, 0.f};
        ushort4 u1, u2, u3;
        split3u(rv.x, u1.x, u2.x, u3.x);
        split3u(rv.y, u1.y, u2.y, u3.y);
        split3u(rv.z, u1.z, u2.z, u3.z);
        split3u(rv.w, u1.w, u2.w, u3.w);
        size_t o = (size_t)b * 768 + lane * 4;
        *reinterpret_cast<ushort4*>(actout + o)             = u1;
        *reinterpret_cast<ushort4*>(actout + o + ACT_S)     = u2;
        *reinterpret_cast<ushort4*>(actout + o + 2 * ACT_S) = u3;
    }
    if (lane < 10) {
        if (t != 0) w_read[(size_t)b * Nsz + lane] = wfr[lane];
        w_write[(size_t)b * Nsz + lane] = wfw[lane];
    }
    // memory update, float4 stores
#pragma unroll
    for (int n = 0; n < 10; n++) {
        float wwn = wfw[n];
        float4 m4 = mreg[n];
        float4 o4;
        o4.x = m4.x * (1.f - er.x * wwn) + ad.x * wwn;
        o4.y = m4.y * (1.f - er.y * wwn) + ad.y * wwn;
        o4.z = m4.z * (1.f - er.z * wwn) + ad.z * wwn;
        o4.w = m4.w * (1.f - er.w * wwn) + ad.w * wwn;
        *reinterpret_cast<float4*>(memb + n * Msz + lane * 4) = o4;
    }
}

// final output: y logits + argmax from headbuf (t=32)
__global__ __launch_bounds__(64) void k_out(
    const float* __restrict__ headbuf, float* __restrict__ d_out)
{
    int b = blockIdx.x * 64 + threadIdx.x;
    if (b >= Bsz) return;
    float4 y = *reinterpret_cast<const float4*>(headbuf + (size_t)b * NHEAD + 1024);
    d_out[(size_t)b * 4 + 0] = y.x;
    d_out[(size_t)b * 4 + 1] = y.y;
    d_out[(size_t)b * 4 + 2] = y.z;
    d_out[(size_t)b * 4 + 3] = y.w;
    int idx = 0; float best = y.x;
    if (y.y > best) { best = y.y; idx = 1; }
    if (y.z > best) { best = y.z; idx = 2; }
    if (y.w > best) { best = y.w; idx = 3; }
    d_out[Bsz * 4 + b] = (float)idx;
}

// ---------------- host ----------------

extern "C" void kernel_launch(void* const* d_in, const int* in_sizes, int n_in,
                              void* d_out, int out_size, void* d_ws, size_t ws_size,
                              hipStream_t stream) {
    const float* z_seq = (const float*)d_in[0];
    const float* W_ih  = (const float*)d_in[1];
    const float* W_hh  = (const float*)d_in[2];
    const float* b_ih  = (const float*)d_in[3];
    const float* b_hh  = (const float*)d_in[4];
    const float* memory_init = (const float*)d_in[31];
    const float* gamma = (const float*)d_in[32];
    const float* beta  = (const float*)d_in[33];

    HeadP hp;
    for (int i = 0; i < 13; i++) {
        hp.W[i] = (const float*)d_in[5 + 2 * i];
        hp.b[i] = (const float*)d_in[6 + 2 * i];
    }

    char* ws = (char*)d_ws;
    size_t off = 0;
    auto alloc = [&](size_t bytes) -> void* {
        off = (off + 255) & ~(size_t)255;
        void* p = ws + off;
        off += bytes;
        return p;
    };
    __hip_bfloat16* zbuf  = (__hip_bfloat16*)alloc(3 * ZPL_S * 2);
    __hip_bfloat16* act   = (__hip_bfloat16*)alloc(2 * 3 * ACT_S * 2);
    float* cbuf    = (float*)alloc((size_t)Bsz * Hsz * 4);
    float* mem     = (float*)alloc((size_t)Bsz * Nsz * Msz * 4);
    float* w_read  = (float*)alloc((size_t)Bsz * Nsz * 4);
    float* w_write = (float*)alloc((size_t)Bsz * Nsz * 4);
    float* headbuf = (float*)alloc((size_t)Bsz * NHEAD * 4);
    __hip_bfloat16* Wg = (__hip_bfloat16*)alloc(3 * WG_S * 2);
    float* bcat    = (float*)alloc((size_t)NGATE * 4);
    __hip_bfloat16* Wh = (__hip_bfloat16*)alloc(3 * WH_S * 2);
    float* bhead   = (float*)alloc((size_t)NHEADP * 4);

    k_prep_wcat<<<(NGATE * KDIM + 255) / 256, 256, 0, stream>>>(W_ih, W_hh, b_ih, b_hh, Wg, bcat);
    k_prep_heads<<<(NHEADP * Hsz + 255) / 256, 256, 0, stream>>>(hp, Wh, bhead);
    k_lnorm<<<(Bsz * Zsz + 255) / 256, 256, 0, stream>>>(z_seq, gamma, beta, zbuf);
    k_init<<<2048, 256, 0, stream>>>(act, cbuf, w_read, w_write, mem, memory_init);

    float* out_f = (float*)d_out;
    for (int t = 0; t < Tsz; t++) {
        const __hip_bfloat16* ain = act + (size_t)(t & 1) * 3 * ACT_S;
        __hip_bfloat16*       aout = act + (size_t)((t + 1) & 1) * 3 * ACT_S;
        k_gates<<<512, 256, 0, stream>>>(
            zbuf + (size_t)t * Bsz * 128, ain, Wg, bcat, cbuf, aout);
        k_heads<<<dim3(16, 18), 256, 0, stream>>>(aout, Wh, bhead, headbuf, 0);
        k_addr3<<<Bsz, 64, 0, stream>>>(headbuf, mem, w_read, w_write, aout, t);
    }
    // t = 32: only y head needed
    {
        const int t = Tsz;
        const __hip_bfloat16* ain = act + (size_t)(t & 1) * 3 * ACT_S;
        __hip_bfloat16*       aout = act + (size_t)((t + 1) & 1) * 3 * ACT_S;
        k_gates<<<512, 256, 0, stream>>>(
            zbuf + (size_t)t * Bsz * 128, ain, Wg, bcat, cbuf, aout);
        k_heads<<<dim3(16, 1), 256, 0, stream>>>(aout, Wh, bhead, headbuf, 16);
        k_out<<<Bsz / 64, 64, 0, stream>>>(headbuf, out_f);
    }
}